// Round 1
// baseline (46617.984 us; speedup 1.0000x reference)
//
#include <hip/hip_runtime.h>
#include <hip/hip_bf16.h>
#include <math.h>

// Problem constants
#define V_SZ 50304
#define C_SZ 768
#define L_SZ 12
#define H_SZ 12
#define HD 64
#define T_SZ 1024
#define B_SZ 4
#define M_SZ (B_SZ * T_SZ)   // 4096 rows
#define C3 (3 * C_SZ)        // 2304
#define C4 (4 * C_SZ)        // 3072

// ---------------------------------------------------------------------------
// Embedding: h[b,t,:] = wte[x[b,t],:] + wpe[t,:]
// ---------------------------------------------------------------------------
__global__ __launch_bounds__(256) void embed_kernel(
    const int* __restrict__ x, const float* __restrict__ wte,
    const float* __restrict__ wpe, float* __restrict__ h) {
  int row = blockIdx.x;             // 0..4095
  int t = row & (T_SZ - 1);
  int tok = x[row];
  const float* wt = wte + (size_t)tok * C_SZ;
  const float* wp = wpe + (size_t)t * C_SZ;
  float* out = h + (size_t)row * C_SZ;
  for (int k = 0; k < 3; k++) {
    int c = threadIdx.x + k * 256;
    out[c] = wt[c] + wp[c];
  }
}

// ---------------------------------------------------------------------------
// LayerNorm: out = (x - mean) * rsqrt(var + 1e-5) * w + b, C=768
// ---------------------------------------------------------------------------
__global__ __launch_bounds__(256) void ln_kernel(
    const float* __restrict__ in, const float* __restrict__ w,
    const float* __restrict__ b, float* __restrict__ out) {
  int row = blockIdx.x;
  int tid = threadIdx.x;
  const float* xr = in + (size_t)row * C_SZ;
  float v0 = xr[tid], v1 = xr[tid + 256], v2 = xr[tid + 512];
  float s = v0 + v1 + v2;
  float ss = v0 * v0 + v1 * v1 + v2 * v2;
  for (int off = 32; off; off >>= 1) {
    s += __shfl_xor(s, off);
    ss += __shfl_xor(ss, off);
  }
  __shared__ float rs[4], rss[4], mv[2];
  int wv = tid >> 6, lane = tid & 63;
  if (lane == 0) { rs[wv] = s; rss[wv] = ss; }
  __syncthreads();
  if (tid == 0) {
    float S = rs[0] + rs[1] + rs[2] + rs[3];
    float SS = rss[0] + rss[1] + rss[2] + rss[3];
    float mean = S * (1.0f / C_SZ);
    float var = SS * (1.0f / C_SZ) - mean * mean;
    mv[0] = mean;
    mv[1] = rsqrtf(var + 1e-5f);
  }
  __syncthreads();
  float mean = mv[0], rstd = mv[1];
  float* orow = out + (size_t)row * C_SZ;
  orow[tid]       = (v0 - mean) * rstd * w[tid]       + b[tid];
  orow[tid + 256] = (v1 - mean) * rstd * w[tid + 256] + b[tid + 256];
  orow[tid + 512] = (v2 - mean) * rstd * w[tid + 512] + b[tid + 512];
}

// ---------------------------------------------------------------------------
// GEMM: C = epilogue(A @ B + bias) (+ residual)
// A [M,K] row-major. B: TRANSB ? [N,K] : [K,N] row-major.
// Tile 128x128, BK=8, 256 threads, 8x8 acc per thread.
// All of M,N divisible by 128, K divisible by 8 for our shapes.
// ---------------------------------------------------------------------------
__device__ __forceinline__ float gelu_f(float x) {
  float x3 = x * x * x;
  return 0.5f * x * (1.0f + tanhf(0.7978845608028654f * (x + 0.044715f * x3)));
}

template <bool TRANSB, bool BIAS, bool GELU_, bool RES>
__global__ __launch_bounds__(256) void gemm_kernel(
    const float* __restrict__ A, const float* __restrict__ B,
    const float* __restrict__ bias, const float* __restrict__ res,
    float* __restrict__ C, int M, int N, int K) {
  __shared__ float As[8][128];
  __shared__ float Bs[8][128];
  int tid = threadIdx.x;
  int m0 = blockIdx.y * 128, n0 = blockIdx.x * 128;
  int tx = tid & 15, ty = tid >> 4;

  float acc[8][8];
#pragma unroll
  for (int i = 0; i < 8; i++)
#pragma unroll
    for (int j = 0; j < 8; j++) acc[i][j] = 0.0f;

  int arow = tid >> 1;            // 0..127
  int ak = (tid & 1) * 4;         // 0 or 4
  int brow = tid >> 5;            // 0..7
  int bn = (tid & 31) * 4;        // 0..124

  for (int k0 = 0; k0 < K; k0 += 8) {
    float4 a4 = *(const float4*)&A[(size_t)(m0 + arow) * K + k0 + ak];
    As[ak + 0][arow] = a4.x;
    As[ak + 1][arow] = a4.y;
    As[ak + 2][arow] = a4.z;
    As[ak + 3][arow] = a4.w;
    if (TRANSB) {
      float4 b4 = *(const float4*)&B[(size_t)(n0 + arow) * K + k0 + ak];
      Bs[ak + 0][arow] = b4.x;
      Bs[ak + 1][arow] = b4.y;
      Bs[ak + 2][arow] = b4.z;
      Bs[ak + 3][arow] = b4.w;
    } else {
      float4 b4 = *(const float4*)&B[(size_t)(k0 + brow) * N + n0 + bn];
      *(float4*)&Bs[brow][bn] = b4;
    }
    __syncthreads();
#pragma unroll
    for (int kk = 0; kk < 8; kk++) {
      float a[8], bb[8];
      *(float4*)&a[0] = *(const float4*)&As[kk][ty * 8];
      *(float4*)&a[4] = *(const float4*)&As[kk][ty * 8 + 4];
      *(float4*)&bb[0] = *(const float4*)&Bs[kk][tx * 8];
      *(float4*)&bb[4] = *(const float4*)&Bs[kk][tx * 8 + 4];
#pragma unroll
      for (int i = 0; i < 8; i++)
#pragma unroll
        for (int j = 0; j < 8; j++) acc[i][j] += a[i] * bb[j];
    }
    __syncthreads();
  }

  float bv[8];
  if (BIAS) {
#pragma unroll
    for (int j = 0; j < 8; j++) bv[j] = bias[n0 + tx * 8 + j];
  }
#pragma unroll
  for (int i = 0; i < 8; i++) {
    size_t mrow = (size_t)(m0 + ty * 8 + i);
    float* crow = &C[mrow * N + n0 + tx * 8];
    float out[8];
#pragma unroll
    for (int j = 0; j < 8; j++) {
      float v = acc[i][j];
      if (BIAS) v += bv[j];
      if (GELU_) v = gelu_f(v);
      out[j] = v;
    }
    if (RES) {
      const float* rrow = &res[mrow * N + n0 + tx * 8];
      float4 r0 = *(const float4*)&rrow[0];
      float4 r1 = *(const float4*)&rrow[4];
      out[0] += r0.x; out[1] += r0.y; out[2] += r0.z; out[3] += r0.w;
      out[4] += r1.x; out[5] += r1.y; out[6] += r1.z; out[7] += r1.w;
    }
    *(float4*)&crow[0] = *(float4*)&out[0];
    *(float4*)&crow[4] = *(float4*)&out[4];
  }
}

// ---------------------------------------------------------------------------
// Attention: per block: one (b, h) and 4 consecutive q rows.
// qkv [4096, 2304]: q at col h*64, k at 768+h*64, v at 1536+h*64.
// No 1/sqrt(hd) scaling (faithful to reference). Causal.
// ---------------------------------------------------------------------------
__global__ __launch_bounds__(256) void attn_kernel(
    const float* __restrict__ qkv, float* __restrict__ att) {
  int b = blockIdx.z, h = blockIdx.y, t0 = blockIdx.x * 4;
  int tid = threadIdx.x;
  __shared__ float qs[4][HD];
  __shared__ float sc[4][T_SZ];

  int r = tid >> 6, lane = tid & 63;
  qs[r][lane] = qkv[(size_t)(b * T_SZ + t0 + r) * C3 + h * HD + lane];
  __syncthreads();

  int jmax = t0 + 3;
  // scores for 4 rows
  for (int j = tid; j <= jmax; j += 256) {
    const float4* kp = (const float4*)&qkv[(size_t)(b * T_SZ + j) * C3 + C_SZ + h * HD];
    float d0 = 0, d1 = 0, d2 = 0, d3 = 0;
#pragma unroll
    for (int q4 = 0; q4 < 16; q4++) {
      float4 k4 = kp[q4];
      int d = q4 * 4;
      d0 += qs[0][d] * k4.x + qs[0][d + 1] * k4.y + qs[0][d + 2] * k4.z + qs[0][d + 3] * k4.w;
      d1 += qs[1][d] * k4.x + qs[1][d + 1] * k4.y + qs[1][d + 2] * k4.z + qs[1][d + 3] * k4.w;
      d2 += qs[2][d] * k4.x + qs[2][d + 1] * k4.y + qs[2][d + 2] * k4.z + qs[2][d + 3] * k4.w;
      d3 += qs[3][d] * k4.x + qs[3][d + 1] * k4.y + qs[3][d + 2] * k4.z + qs[3][d + 3] * k4.w;
    }
    sc[0][j] = d0; sc[1][j] = d1; sc[2][j] = d2; sc[3][j] = d3;
  }
  __syncthreads();

  // per-wave softmax: wave `r` owns q row t0+r; lanes cover keys / dims
  int row = r;
  int tr = t0 + row;
  float m = -INFINITY;
  for (int j = lane; j <= tr; j += 64) m = fmaxf(m, sc[row][j]);
#pragma unroll
  for (int off = 32; off; off >>= 1) m = fmaxf(m, __shfl_xor(m, off));
  float s = 0.0f;
  for (int j = lane; j <= tr; j += 64) {
    float e = __expf(sc[row][j] - m);
    sc[row][j] = e;
    s += e;
  }
#pragma unroll
  for (int off = 32; off; off >>= 1) s += __shfl_xor(s, off);
  float inv = 1.0f / s;

  // PV: lane = output dim d
  float acc = 0.0f;
  const float* vbase = &qkv[(size_t)(b * T_SZ) * C3 + 2 * C_SZ + h * HD + lane];
#pragma unroll 4
  for (int j = 0; j <= tr; j++) acc += sc[row][j] * vbase[(size_t)j * C3];
  att[(size_t)(b * T_SZ + tr) * C_SZ + h * HD + lane] = acc * inv;
}

// ---------------------------------------------------------------------------
// Online logsumexp per row over V=50304
// ---------------------------------------------------------------------------
__global__ __launch_bounds__(256) void lse_kernel(
    const float* __restrict__ logits, float* __restrict__ lse) {
  int row = blockIdx.x, tid = threadIdx.x;
  const float* xr = logits + (size_t)row * V_SZ;
  float m = -INFINITY, s = 0.0f;
  for (int v = tid; v < V_SZ; v += 256) {
    float z = xr[v];
    if (z > m) {
      s = s * __expf(m - z) + 1.0f;
      m = z;
    } else {
      s += __expf(z - m);
    }
  }
#pragma unroll
  for (int off = 32; off; off >>= 1) {
    float mo = __shfl_xor(m, off), so = __shfl_xor(s, off);
    float M2 = fmaxf(m, mo);
    s = s * __expf(m - M2) + so * __expf(mo - M2);
    m = M2;
  }
  __shared__ float rm[4], rsum[4];
  int wv = tid >> 6, lane = tid & 63;
  if (lane == 0) { rm[wv] = m; rsum[wv] = s; }
  __syncthreads();
  if (tid == 0) {
    float M = rm[0], S = rsum[0];
    for (int w = 1; w < 4; w++) {
      float M2 = fmaxf(M, rm[w]);
      S = S * __expf(M - M2) + rsum[w] * __expf(rm[w] - M2);
      M = M2;
    }
    lse[row] = M + logf(S);
  }
}

// ---------------------------------------------------------------------------
// Loss: -mean(logits[target] - lse) over 4096 rows, single block
// ---------------------------------------------------------------------------
__global__ __launch_bounds__(256) void loss_kernel(
    const float* __restrict__ logits, const int* __restrict__ targets,
    const float* __restrict__ lse, float* __restrict__ out_loss) {
  int tid = threadIdx.x;
  float acc = 0.0f;
  for (int i = tid; i < M_SZ; i += 256) {
    acc += lse[i] - logits[(size_t)i * V_SZ + targets[i]];
  }
#pragma unroll
  for (int off = 32; off; off >>= 1) acc += __shfl_xor(acc, off);
  __shared__ float rs[4];
  int wv = tid >> 6, lane = tid & 63;
  if (lane == 0) rs[wv] = acc;
  __syncthreads();
  if (tid == 0) out_loss[0] = (rs[0] + rs[1] + rs[2] + rs[3]) * (1.0f / M_SZ);
}

// ---------------------------------------------------------------------------
extern "C" void kernel_launch(void* const* d_in, const int* in_sizes, int n_in,
                              void* d_out, int out_size, void* d_ws, size_t ws_size,
                              hipStream_t stream) {
  const int* x        = (const int*)d_in[0];
  const int* targets  = (const int*)d_in[1];
  const float* wte    = (const float*)d_in[2];
  const float* wpe    = (const float*)d_in[3];
  const float* ln1_w  = (const float*)d_in[4];
  const float* ln1_b  = (const float*)d_in[5];
  const float* attn_w = (const float*)d_in[6];
  const float* attn_b = (const float*)d_in[7];
  const float* proj_w = (const float*)d_in[8];
  const float* proj_b = (const float*)d_in[9];
  const float* ln2_w  = (const float*)d_in[10];
  const float* ln2_b  = (const float*)d_in[11];
  const float* fc_w   = (const float*)d_in[12];
  const float* fc_b   = (const float*)d_in[13];
  const float* fc2_w  = (const float*)d_in[14];
  const float* fc2_b  = (const float*)d_in[15];
  const float* lnf_w  = (const float*)d_in[16];
  const float* lnf_b  = (const float*)d_in[17];

  // workspace layout (fp32)
  float* h   = (float*)d_ws;                    // [4096,768]
  float* hn  = h   + (size_t)M_SZ * C_SZ;       // [4096,768]
  float* qkv = hn  + (size_t)M_SZ * C_SZ;       // [4096,2304]
  float* att = qkv + (size_t)M_SZ * C3;         // [4096,768]
  float* fcb = att + (size_t)M_SZ * C_SZ;       // [4096,3072]
  float* lse = fcb + (size_t)M_SZ * C4;         // [4096]

  float* logits = (float*)d_out;
  float* loss_out = logits + (size_t)M_SZ * V_SZ;

  embed_kernel<<<M_SZ, 256, 0, stream>>>(x, wte, wpe, h);

  for (int l = 0; l < L_SZ; l++) {
    ln_kernel<<<M_SZ, 256, 0, stream>>>(h, ln1_w + l * C_SZ, ln1_b + l * C_SZ, hn);
    gemm_kernel<false, true, false, false><<<dim3(C3 / 128, M_SZ / 128), 256, 0, stream>>>(
        hn, attn_w + (size_t)l * C_SZ * C3, attn_b + (size_t)l * C3, nullptr, qkv,
        M_SZ, C3, C_SZ);
    attn_kernel<<<dim3(T_SZ / 4, H_SZ, B_SZ), 256, 0, stream>>>(qkv, att);
    gemm_kernel<false, true, false, true><<<dim3(C_SZ / 128, M_SZ / 128), 256, 0, stream>>>(
        att, proj_w + (size_t)l * C_SZ * C_SZ, proj_b + (size_t)l * C_SZ, h, h,
        M_SZ, C_SZ, C_SZ);
    ln_kernel<<<M_SZ, 256, 0, stream>>>(h, ln2_w + l * C_SZ, ln2_b + l * C_SZ, hn);
    gemm_kernel<false, true, true, false><<<dim3(C4 / 128, M_SZ / 128), 256, 0, stream>>>(
        hn, fc_w + (size_t)l * C_SZ * C4, fc_b + (size_t)l * C4, nullptr, fcb,
        M_SZ, C4, C_SZ);
    gemm_kernel<false, true, false, true><<<dim3(C_SZ / 128, M_SZ / 128), 256, 0, stream>>>(
        fcb, fc2_w + (size_t)l * C4 * C_SZ, fc2_b + (size_t)l * C_SZ, h, h,
        M_SZ, C_SZ, C4);
  }

  ln_kernel<<<M_SZ, 256, 0, stream>>>(h, lnf_w, lnf_b, hn);
  // logits = hn @ wte^T  (B is [V, C] row-major -> TRANSB)
  gemm_kernel<true, false, false, false><<<dim3(V_SZ / 128, M_SZ / 128), 256, 0, stream>>>(
      hn, wte, nullptr, nullptr, logits, M_SZ, V_SZ, C_SZ);

  lse_kernel<<<M_SZ, 256, 0, stream>>>(logits, lse);
  loss_kernel<<<1, 256, 0, stream>>>(logits, targets, lse, loss_out);
}